// Round 2
// baseline (65.056 us; speedup 1.0000x reference)
//
#include <hip/hip_runtime.h>
#include <stdint.h>

typedef __bf16 bf16;
typedef __bf16 bf16x8 __attribute__((ext_vector_type(8)));
typedef float f32x4 __attribute__((ext_vector_type(4)));

#define NB    2
#define LQn   2048
#define LKVn  1024
#define DM    512
#define NH    8
#define HD    64

static __device__ __forceinline__ f32x4 mfma_bf16(bf16x8 a, bf16x8 b, f32x4 c) {
  return __builtin_amdgcn_mfma_f32_16x16x32_bf16(a, b, c, 0, 0, 0);
}

// ---------- weight transpose+convert: WThi/WTlo[n*512+k] from W[k*512+n]
// hi for all 4 mats; lo only for Wq (mat 0) and Wk (mat 1).
__global__ __launch_bounds__(256) void transpose_w_kernel(
    const float* __restrict__ Wq, const float* __restrict__ Wk,
    const float* __restrict__ Wv, const float* __restrict__ Wo,
    bf16* __restrict__ WThi, bf16* __restrict__ WTlo) {
  __shared__ float tile[64 * 65];
  const int bid = blockIdx.x;
  const int mat = bid >> 6;
  const int tb  = bid & 63;
  const int r0 = (tb >> 3) * 64;  // k block
  const int c0 = (tb & 7) * 64;   // n block
  const float* W = (mat == 0) ? Wq : (mat == 1) ? Wk : (mat == 2) ? Wv : Wo;
  const int t = threadIdx.x;
#pragma unroll
  for (int i = 0; i < 16; ++i) {
    int idx = i * 256 + t;
    int r = idx >> 6, c = idx & 63;
    tile[r * 65 + c] = W[(size_t)(r0 + r) * DM + c0 + c];
  }
  __syncthreads();
#pragma unroll
  for (int i = 0; i < 16; ++i) {
    int idx = i * 256 + t;
    int r = idx >> 6, c = idx & 63;  // out row n=c0+r, col k=r0+c
    float x = tile[c * 65 + r];
    bf16 h = (bf16)x;
    size_t off = (size_t)(c0 + r) * DM + r0 + c;
    WThi[(size_t)mat * DM * DM + off] = h;
    if (mat < 2) WTlo[(size_t)mat * DM * DM + off] = (bf16)(x - (float)h);
  }
}

// ---------- plain 128x128 GEMM tile: C = A @ WT^T  (K=512)
template <bool A_F32, bool OUT_F32>
__device__ __forceinline__ void gemm128(const void* __restrict__ Ap,
                                        const bf16* __restrict__ WTp,
                                        void* __restrict__ Cp, int m0, int n0,
                                        bf16* smA, bf16* smB) {
  const int t = threadIdx.x;
  const int lane = t & 63;
  const int w = t >> 6;
  const int ln = lane & 15, hi = lane >> 4;
  const int wr = w >> 1, wc = w & 1;
  const f32x4 zf = {0.f, 0.f, 0.f, 0.f};
  f32x4 acc[4][4];
#pragma unroll
  for (int a = 0; a < 4; ++a)
#pragma unroll
    for (int b = 0; b < 4; ++b) acc[a][b] = zf;

  for (int k0 = 0; k0 < 512; k0 += 64) {
    bf16x8 avb[4], bvb[4];
#pragma unroll
    for (int i = 0; i < 4; ++i) {
      int c = i * 256 + t;
      int r = c >> 3, col = (c & 7) * 8;
      if constexpr (A_F32) {
        const float* g = (const float*)Ap + (size_t)(m0 + r) * 512 + k0 + col;
        f32x4 x0 = *(const f32x4*)g;
        f32x4 x1 = *(const f32x4*)(g + 4);
        bf16x8 pk;
#pragma unroll
        for (int e = 0; e < 4; ++e) { pk[e] = (bf16)x0[e]; pk[4 + e] = (bf16)x1[e]; }
        avb[i] = pk;
      } else {
        avb[i] = *(const bf16x8*)((const bf16*)Ap + (size_t)(m0 + r) * 512 + k0 + col);
      }
      bvb[i] = *(const bf16x8*)(WTp + (size_t)(n0 + r) * 512 + k0 + col);
    }
    __syncthreads();
#pragma unroll
    for (int i = 0; i < 4; ++i) {
      int c = i * 256 + t;
      int r = c >> 3, col = (c & 7) * 8;
      *(bf16x8*)&smA[r * 64 + col] = avb[i];
      *(bf16x8*)&smB[r * 64 + col] = bvb[i];
    }
    __syncthreads();
#pragma unroll
    for (int kk = 0; kk < 64; kk += 32) {
      bf16x8 af[4], bb[4];
#pragma unroll
      for (int mf = 0; mf < 4; ++mf)
        af[mf] = *(const bf16x8*)&smA[(wr * 64 + mf * 16 + ln) * 64 + kk + hi * 8];
#pragma unroll
      for (int nf = 0; nf < 4; ++nf)
        bb[nf] = *(const bf16x8*)&smB[(wc * 64 + nf * 16 + ln) * 64 + kk + hi * 8];
#pragma unroll
      for (int mf = 0; mf < 4; ++mf)
#pragma unroll
        for (int nf = 0; nf < 4; ++nf)
          acc[mf][nf] = mfma_bf16(af[mf], bb[nf], acc[mf][nf]);
    }
  }
#pragma unroll
  for (int mf = 0; mf < 4; ++mf)
#pragma unroll
    for (int nf = 0; nf < 4; ++nf)
#pragma unroll
      for (int r = 0; r < 4; ++r) {
        size_t off = (size_t)(m0 + wr * 64 + mf * 16 + hi * 4 + r) * 512 +
                     n0 + wc * 64 + nf * 16 + ln;
        if constexpr (OUT_F32) ((float*)Cp)[off] = acc[mf][nf][r];
        else ((bf16*)Cp)[off] = (bf16)acc[mf][nf][r];
      }
}

// ---------- split-precision 128x128 GEMM tile: fp32 A, hi/lo bf16 B -> fp32 C
// acc = Ah*Bh + Ah*Bl + Al*Bh  (~fp32-accurate)
__device__ __forceinline__ void gemm128_split(const float* __restrict__ Ap,
                                              const bf16* __restrict__ Bh,
                                              const bf16* __restrict__ Bl,
                                              float* __restrict__ Cp, int m0, int n0,
                                              bf16* smAh, bf16* smAl,
                                              bf16* smBh, bf16* smBl) {
  const int t = threadIdx.x;
  const int lane = t & 63;
  const int w = t >> 6;
  const int ln = lane & 15, hi = lane >> 4;
  const int wr = w >> 1, wc = w & 1;
  const f32x4 zf = {0.f, 0.f, 0.f, 0.f};
  f32x4 acc[4][4];
#pragma unroll
  for (int a = 0; a < 4; ++a)
#pragma unroll
    for (int b = 0; b < 4; ++b) acc[a][b] = zf;

  for (int k0 = 0; k0 < 512; k0 += 64) {
    bf16x8 avh[4], avl[4], bvh[4], bvl[4];
#pragma unroll
    for (int i = 0; i < 4; ++i) {
      int c = i * 256 + t;
      int r = c >> 3, col = (c & 7) * 8;
      const float* g = Ap + (size_t)(m0 + r) * 512 + k0 + col;
      f32x4 x0 = *(const f32x4*)g;
      f32x4 x1 = *(const f32x4*)(g + 4);
      bf16x8 hv, lv;
#pragma unroll
      for (int e = 0; e < 4; ++e) {
        float x = x0[e]; bf16 hh = (bf16)x; hv[e] = hh; lv[e] = (bf16)(x - (float)hh);
        float y = x1[e]; bf16 h2 = (bf16)y; hv[4 + e] = h2; lv[4 + e] = (bf16)(y - (float)h2);
      }
      avh[i] = hv; avl[i] = lv;
      bvh[i] = *(const bf16x8*)(Bh + (size_t)(n0 + r) * 512 + k0 + col);
      bvl[i] = *(const bf16x8*)(Bl + (size_t)(n0 + r) * 512 + k0 + col);
    }
    __syncthreads();
#pragma unroll
    for (int i = 0; i < 4; ++i) {
      int c = i * 256 + t;
      int r = c >> 3, col = (c & 7) * 8;
      *(bf16x8*)&smAh[r * 64 + col] = avh[i];
      *(bf16x8*)&smAl[r * 64 + col] = avl[i];
      *(bf16x8*)&smBh[r * 64 + col] = bvh[i];
      *(bf16x8*)&smBl[r * 64 + col] = bvl[i];
    }
    __syncthreads();
#pragma unroll
    for (int kk = 0; kk < 64; kk += 32) {
      bf16x8 ah[4], al[4], bh[4], bl[4];
#pragma unroll
      for (int mf = 0; mf < 4; ++mf) {
        ah[mf] = *(const bf16x8*)&smAh[(wr * 64 + mf * 16 + ln) * 64 + kk + hi * 8];
        al[mf] = *(const bf16x8*)&smAl[(wr * 64 + mf * 16 + ln) * 64 + kk + hi * 8];
      }
#pragma unroll
      for (int nf = 0; nf < 4; ++nf) {
        bh[nf] = *(const bf16x8*)&smBh[(wc * 64 + nf * 16 + ln) * 64 + kk + hi * 8];
        bl[nf] = *(const bf16x8*)&smBl[(wc * 64 + nf * 16 + ln) * 64 + kk + hi * 8];
      }
#pragma unroll
      for (int mf = 0; mf < 4; ++mf)
#pragma unroll
        for (int nf = 0; nf < 4; ++nf) {
          acc[mf][nf] = mfma_bf16(ah[mf], bh[nf], acc[mf][nf]);
          acc[mf][nf] = mfma_bf16(ah[mf], bl[nf], acc[mf][nf]);
          acc[mf][nf] = mfma_bf16(al[mf], bh[nf], acc[mf][nf]);
        }
    }
  }
#pragma unroll
  for (int mf = 0; mf < 4; ++mf)
#pragma unroll
    for (int nf = 0; nf < 4; ++nf)
#pragma unroll
      for (int r = 0; r < 4; ++r) {
        size_t off = (size_t)(m0 + wr * 64 + mf * 16 + hi * 4 + r) * 512 +
                     n0 + wc * 64 + nf * 16 + ln;
        Cp[off] = acc[mf][nf][r];
      }
}

// ---------- fused Q/K/V projection. Q,K split-precision fp32 out; V plain bf16.
__global__ __launch_bounds__(256) void proj_kernel(
    const float* __restrict__ q, const float* __restrict__ k,
    const float* __restrict__ v, const bf16* __restrict__ WThi,
    const bf16* __restrict__ WTlo,
    float* __restrict__ Qf, float* __restrict__ Kf, bf16* __restrict__ Vb) {
  __shared__ bf16 sm0[128 * 64];
  __shared__ bf16 sm1[128 * 64];
  __shared__ bf16 sm2[128 * 64];
  __shared__ bf16 sm3[128 * 64];
  const int bid = blockIdx.x;
  if (bid < 128) {            // Q: 32x4 tiles, split
    int m0 = (bid >> 2) * 128, n0 = (bid & 3) * 128;
    gemm128_split(q, WThi, WTlo, Qf, m0, n0, sm0, sm1, sm2, sm3);
  } else if (bid < 192) {     // K: 16x4 tiles, split
    int b2 = bid - 128;
    int m0 = (b2 >> 2) * 128, n0 = (b2 & 3) * 128;
    gemm128_split(k, WThi + (size_t)DM * DM, WTlo + (size_t)DM * DM, Kf, m0, n0,
                  sm0, sm1, sm2, sm3);
  } else {                    // V: 16x4 tiles, plain
    int b2 = bid - 192;
    int m0 = (b2 >> 2) * 128, n0 = (b2 & 3) * 128;
    gemm128<true, false>(v, WThi + (size_t)2 * DM * DM, Vb, m0, n0, sm0, sm2);
  }
}

// ---------- output projection (plain bf16)
__global__ __launch_bounds__(256) void outproj_kernel(
    const bf16* __restrict__ AO, const bf16* __restrict__ WoT,
    float* __restrict__ out) {
  __shared__ bf16 smA[128 * 64];
  __shared__ bf16 smB[128 * 64];
  const int bid = blockIdx.x;
  int m0 = (bid >> 2) * 128, n0 = (bid & 3) * 128;
  gemm128<false, true>(AO, WoT, out, m0, n0, smA, smB);
}

// ---------- banded attention: one (b, h, 128-query tile) per block
// Q,K fp32 in, staged as hi/lo bf16; scores ~fp32-accurate.
__global__ __launch_bounds__(256) void attn_kernel(
    const float* __restrict__ Qf, const float* __restrict__ Kf,
    const bf16* __restrict__ Vb, bf16* __restrict__ AO) {
  __shared__ bf16 smQh[128 * 64];
  __shared__ bf16 smQl[128 * 64];
  __shared__ bf16 smKh[128 * 64];
  __shared__ bf16 smKl[128 * 64];
  __shared__ bf16 smVt[64 * 128];   // smVt[d][p]
  __shared__ bf16 smP[128 * 128];
  const int bid = blockIdx.x;
  const int qt = bid & 15;
  const int h  = (bid >> 4) & 7;
  const int b  = bid >> 7;
  const int j0 = qt * 128;
  const int c0 = j0 >> 1;
  const int pbase = c0 - 63;       // KV tile rows: pbase .. pbase+127
  const int t = threadIdx.x;
  const int lane = t & 63, w = t >> 6;
  const int ln = lane & 15, hi = lane >> 4;

  // stage Q, K (hi/lo, row-major [128][64]) and V transposed ([64][128])
#pragma unroll
  for (int i = 0; i < 4; ++i) {
    int c = i * 256 + t;
    int r = c >> 3, d8 = (c & 7) * 8;
    {
      const float* g = Qf + ((size_t)(b * LQn + j0 + r)) * 512 + h * 64 + d8;
      f32x4 x0 = *(const f32x4*)g, x1 = *(const f32x4*)(g + 4);
      bf16x8 hv, lv;
#pragma unroll
      for (int e = 0; e < 4; ++e) {
        float x = x0[e]; bf16 hh = (bf16)x; hv[e] = hh; lv[e] = (bf16)(x - (float)hh);
        float y = x1[e]; bf16 h2 = (bf16)y; hv[4+e] = h2; lv[4+e] = (bf16)(y - (float)h2);
      }
      *(bf16x8*)&smQh[r * 64 + d8] = hv;
      *(bf16x8*)&smQl[r * 64 + d8] = lv;
    }
    int p = pbase + r;
    p = p < 0 ? 0 : (p > LKVn - 1 ? LKVn - 1 : p);  // clamped rows masked later
    {
      const float* g = Kf + ((size_t)(b * LKVn + p)) * 512 + h * 64 + d8;
      f32x4 x0 = *(const f32x4*)g, x1 = *(const f32x4*)(g + 4);
      bf16x8 hv, lv;
#pragma unroll
      for (int e = 0; e < 4; ++e) {
        float x = x0[e]; bf16 hh = (bf16)x; hv[e] = hh; lv[e] = (bf16)(x - (float)hh);
        float y = x1[e]; bf16 h2 = (bf16)y; hv[4+e] = h2; lv[4+e] = (bf16)(y - (float)h2);
      }
      *(bf16x8*)&smKh[r * 64 + d8] = hv;
      *(bf16x8*)&smKl[r * 64 + d8] = lv;
    }
    bf16x8 vv = *(const bf16x8*)(Vb + ((size_t)(b * LKVn + p)) * 512 + h * 64 + d8);
#pragma unroll
    for (int e = 0; e < 8; ++e) smVt[(d8 + e) * 128 + r] = vv[e];
  }
  __syncthreads();

  // S = Q K^T  split: Qh*Kh + Qh*Kl + Ql*Kh
  const f32x4 zf = {0.f, 0.f, 0.f, 0.f};
  f32x4 s[2][8];
#pragma unroll
  for (int mf = 0; mf < 2; ++mf)
#pragma unroll
    for (int cf = 0; cf < 8; ++cf) s[mf][cf] = zf;
#pragma unroll
  for (int kk = 0; kk < 64; kk += 32) {
    bf16x8 ah[2], al[2], bh[8], blv[8];
#pragma unroll
    for (int mf = 0; mf < 2; ++mf) {
      ah[mf] = *(const bf16x8*)&smQh[(w * 32 + mf * 16 + ln) * 64 + kk + hi * 8];
      al[mf] = *(const bf16x8*)&smQl[(w * 32 + mf * 16 + ln) * 64 + kk + hi * 8];
    }
#pragma unroll
    for (int cf = 0; cf < 8; ++cf) {
      bh[cf]  = *(const bf16x8*)&smKh[(cf * 16 + ln) * 64 + kk + hi * 8];
      blv[cf] = *(const bf16x8*)&smKl[(cf * 16 + ln) * 64 + kk + hi * 8];
    }
#pragma unroll
    for (int mf = 0; mf < 2; ++mf)
#pragma unroll
      for (int cf = 0; cf < 8; ++cf) {
        s[mf][cf] = mfma_bf16(ah[mf], bh[cf],  s[mf][cf]);
        s[mf][cf] = mfma_bf16(ah[mf], blv[cf], s[mf][cf]);
        s[mf][cf] = mfma_bf16(al[mf], bh[cf],  s[mf][cf]);
      }
  }

  // mask (band + left clamp), wave-parallel softmax, P -> bf16 LDS
#pragma unroll
  for (int mf = 0; mf < 2; ++mf) {
#pragma unroll
    for (int r = 0; r < 4; ++r) {
      int rloc = w * 32 + mf * 16 + hi * 4 + r;
      int wlo = rloc >> 1;
      int colmin = wlo > -pbase ? wlo : -pbase;
      int colmax = wlo + 63;
      float sv[8];
      float mx = -1e30f;
#pragma unroll
      for (int cf = 0; cf < 8; ++cf) {
        int col = cf * 16 + ln;
        float val = s[mf][cf][r];
        bool ok = (col >= colmin) && (col <= colmax);
        sv[cf] = ok ? val : -1e30f;
        mx = fmaxf(mx, sv[cf]);
      }
#pragma unroll
      for (int msk = 1; msk < 16; msk <<= 1) mx = fmaxf(mx, __shfl_xor(mx, msk, 64));
      float sum = 0.f;
#pragma unroll
      for (int cf = 0; cf < 8; ++cf) {
        sv[cf] = __expf(sv[cf] - mx);
        sum += sv[cf];
      }
#pragma unroll
      for (int msk = 1; msk < 16; msk <<= 1) sum += __shfl_xor(sum, msk, 64);
      float rs = 1.0f / sum;
#pragma unroll
      for (int cf = 0; cf < 8; ++cf)
        smP[rloc * 128 + cf * 16 + ln] = (bf16)(sv[cf] * rs);
    }
  }
  __syncthreads();

  // O = P @ V   (wave's 32 q-rows x 64 d)
  f32x4 o[2][4];
#pragma unroll
  for (int mf = 0; mf < 2; ++mf)
#pragma unroll
    for (int nf = 0; nf < 4; ++nf) o[mf][nf] = zf;
#pragma unroll
  for (int kk = 0; kk < 128; kk += 32) {
    bf16x8 pa[2], vb[4];
#pragma unroll
    for (int mf = 0; mf < 2; ++mf)
      pa[mf] = *(const bf16x8*)&smP[(w * 32 + mf * 16 + ln) * 128 + kk + hi * 8];
#pragma unroll
    for (int nf = 0; nf < 4; ++nf)
      vb[nf] = *(const bf16x8*)&smVt[(nf * 16 + ln) * 128 + kk + hi * 8];
#pragma unroll
    for (int mf = 0; mf < 2; ++mf)
#pragma unroll
      for (int nf = 0; nf < 4; ++nf)
        o[mf][nf] = mfma_bf16(pa[mf], vb[nf], o[mf][nf]);
  }

  // write AO[b, j0+rloc, h*64 + d]
#pragma unroll
  for (int mf = 0; mf < 2; ++mf)
#pragma unroll
    for (int nf = 0; nf < 4; ++nf)
#pragma unroll
      for (int r = 0; r < 4; ++r) {
        int rloc = w * 32 + mf * 16 + hi * 4 + r;
        AO[((size_t)(b * LQn + j0 + rloc)) * 512 + h * 64 + nf * 16 + ln] =
            (bf16)o[mf][nf][r];
      }
}

extern "C" void kernel_launch(void* const* d_in, const int* in_sizes, int n_in,
                              void* d_out, int out_size, void* d_ws, size_t ws_size,
                              hipStream_t stream) {
  const float* q    = (const float*)d_in[0];
  const float* k    = (const float*)d_in[1];
  const float* v    = (const float*)d_in[2];
  const float* Wq   = (const float*)d_in[3];
  const float* Wk   = (const float*)d_in[4];
  const float* Wv   = (const float*)d_in[5];
  const float* Wout = (const float*)d_in[6];
  float* out = (float*)d_out;

  char* ws = (char*)d_ws;
  bf16*  WThi = (bf16*)ws;                          // 4*512*512*2 = 2 MB
  bf16*  WTlo = (bf16*)(ws + (size_t)(2  << 20));   // 2*512*512*2 = 1 MB
  float* Qf   = (float*)(ws + (size_t)(3  << 20));  // 4096*512*4 = 8 MB
  float* Kf   = (float*)(ws + (size_t)(11 << 20));  // 2048*512*4 = 4 MB
  bf16*  Vbuf = (bf16*)(ws + (size_t)(15 << 20));   // 2048*512*2 = 2 MB
  bf16*  AO   = (bf16*)(ws + (size_t)(17 << 20));   // 4096*512*2 = 4 MB (total 21 MB)

  transpose_w_kernel<<<256, 256, 0, stream>>>(Wq, Wk, Wv, Wout, WThi, WTlo);
  proj_kernel<<<256, 256, 0, stream>>>(q, k, v, WThi, WTlo, Qf, Kf, Vbuf);
  attn_kernel<<<256, 256, 0, stream>>>(Qf, Kf, Vbuf, AO);
  outproj_kernel<<<128, 256, 0, stream>>>(AO, WThi + (size_t)3 * DM * DM, out);
}

// Round 3
// 46.031 us; speedup vs baseline: 1.4133x; 1.4133x over previous
//
#include <hip/hip_runtime.h>
#include <stdint.h>

typedef __bf16 bf16;
typedef __bf16 bf16x8 __attribute__((ext_vector_type(8)));
typedef float f32x4 __attribute__((ext_vector_type(4)));

#define NB    2
#define LQn   2048
#define LKVn  1024
#define DM    512
#define NH    8
#define HD    64

static __device__ __forceinline__ f32x4 mfma_bf16(bf16x8 a, bf16x8 b, f32x4 c) {
  return __builtin_amdgcn_mfma_f32_16x16x32_bf16(a, b, c, 0, 0, 0);
}

// ---------- weight transpose+convert: WThi[mat][n*512+k] = (bf16)W[k*512+n]
__global__ __launch_bounds__(256) void transpose_w_kernel(
    const float* __restrict__ Wq, const float* __restrict__ Wk,
    const float* __restrict__ Wv, const float* __restrict__ Wo,
    bf16* __restrict__ WThi) {
  __shared__ float tile[64 * 65];
  const int bid = blockIdx.x;
  const int mat = bid >> 6;
  const int tb  = bid & 63;
  const int r0 = (tb >> 3) * 64;  // k block
  const int c0 = (tb & 7) * 64;   // n block
  const float* W = (mat == 0) ? Wq : (mat == 1) ? Wk : (mat == 2) ? Wv : Wo;
  const int t = threadIdx.x;
#pragma unroll
  for (int i = 0; i < 16; ++i) {
    int idx = i * 256 + t;
    int r = idx >> 6, c = idx & 63;
    tile[r * 65 + c] = W[(size_t)(r0 + r) * DM + c0 + c];
  }
  __syncthreads();
#pragma unroll
  for (int i = 0; i < 16; ++i) {
    int idx = i * 256 + t;
    int r = idx >> 6, c = idx & 63;  // out row n=c0+r, col k=r0+c
    WThi[(size_t)mat * DM * DM + (size_t)(c0 + r) * DM + r0 + c] =
        (bf16)tile[c * 65 + r];
  }
}

// ---------- projection tile 128x128, 512 threads (8 waves, 2M x 4N).
// SPLIT: A=fp32 -> hi/lo, acc = Ah*B + Al*B, out hi/lo bf16.
// !SPLIT: A=fp32 -> bf16, acc = A*B, out bf16.
template <bool SPLIT>
__device__ __forceinline__ void proj_tile(const float* __restrict__ Ap,
                                          const bf16* __restrict__ Bp,
                                          bf16* __restrict__ Chi,
                                          bf16* __restrict__ Clo,
                                          int m0, int n0,
                                          bf16* smAh, bf16* smAl, bf16* smBh) {
  const int t = threadIdx.x;
  const int lane = t & 63;
  const int w = t >> 6;            // 0..7
  const int ln = lane & 15, hi4 = lane >> 4;
  const int wr = w >> 2, wc = w & 3;
  const f32x4 zf = {0.f, 0.f, 0.f, 0.f};
  f32x4 acc[4][2];
#pragma unroll
  for (int a = 0; a < 4; ++a)
#pragma unroll
    for (int b = 0; b < 2; ++b) acc[a][b] = zf;

  for (int k0 = 0; k0 < 512; k0 += 64) {
    bf16x8 ahv[2], alv[2], bv[2];
#pragma unroll
    for (int i = 0; i < 2; ++i) {
      int idx = i * 512 + t;        // 0..1023 units of 8 elems
      int r = idx >> 3, u = idx & 7;
      const float* g = Ap + (size_t)(m0 + r) * 512 + k0 + u * 8;
      f32x4 x0 = *(const f32x4*)g, x1 = *(const f32x4*)(g + 4);
      bf16x8 hv, lv;
#pragma unroll
      for (int e = 0; e < 4; ++e) {
        float x = x0[e]; bf16 hh = (bf16)x; hv[e] = hh;
        float y = x1[e]; bf16 h2 = (bf16)y; hv[4 + e] = h2;
        if constexpr (SPLIT) { lv[e] = (bf16)(x - (float)hh); lv[4 + e] = (bf16)(y - (float)h2); }
      }
      ahv[i] = hv; alv[i] = lv;
      bv[i] = *(const bf16x8*)(Bp + (size_t)(n0 + r) * 512 + k0 + u * 8);
    }
    __syncthreads();
#pragma unroll
    for (int i = 0; i < 2; ++i) {
      int idx = i * 512 + t;
      int r = idx >> 3, u = idx & 7;
      int sw = r * 64 + ((u ^ (r & 7)) * 8);
      *(bf16x8*)&smAh[sw] = ahv[i];
      if constexpr (SPLIT) *(bf16x8*)&smAl[sw] = alv[i];
      *(bf16x8*)&smBh[sw] = bv[i];
    }
    __syncthreads();
#pragma unroll
    for (int kk = 0; kk < 64; kk += 32) {
      const int ub = kk >> 3;
      bf16x8 ah[4], al[4], bh[2];
#pragma unroll
      for (int mf = 0; mf < 4; ++mf) {
        int row = wr * 64 + mf * 16 + ln;
        int addr = row * 64 + (((ub + hi4) ^ (ln & 7)) * 8);
        ah[mf] = *(const bf16x8*)&smAh[addr];
        if constexpr (SPLIT) al[mf] = *(const bf16x8*)&smAl[addr];
      }
#pragma unroll
      for (int nf = 0; nf < 2; ++nf) {
        int row = wc * 32 + nf * 16 + ln;
        int addr = row * 64 + (((ub + hi4) ^ (ln & 7)) * 8);
        bh[nf] = *(const bf16x8*)&smBh[addr];
      }
#pragma unroll
      for (int mf = 0; mf < 4; ++mf)
#pragma unroll
        for (int nf = 0; nf < 2; ++nf) {
          acc[mf][nf] = mfma_bf16(ah[mf], bh[nf], acc[mf][nf]);
          if constexpr (SPLIT) acc[mf][nf] = mfma_bf16(al[mf], bh[nf], acc[mf][nf]);
        }
    }
  }
#pragma unroll
  for (int mf = 0; mf < 4; ++mf)
#pragma unroll
    for (int nf = 0; nf < 2; ++nf)
#pragma unroll
      for (int e = 0; e < 4; ++e) {
        size_t off = (size_t)(m0 + wr * 64 + mf * 16 + hi4 * 4 + e) * 512 +
                     n0 + wc * 32 + nf * 16 + ln;
        float x = acc[mf][nf][e];
        bf16 h = (bf16)x;
        Chi[off] = h;
        if constexpr (SPLIT) Clo[off] = (bf16)(x - (float)h);
      }
}

// ---------- fused Q/K/V projection (Q,K split hi/lo out; V plain bf16)
__global__ __launch_bounds__(512, 2) void proj_kernel(
    const float* __restrict__ q, const float* __restrict__ k,
    const float* __restrict__ v, const bf16* __restrict__ WThi,
    bf16* __restrict__ Qhi, bf16* __restrict__ Qlo,
    bf16* __restrict__ Khi, bf16* __restrict__ Klo, bf16* __restrict__ Vb) {
  __shared__ bf16 smAh[128 * 64];
  __shared__ bf16 smAl[128 * 64];
  __shared__ bf16 smBh[128 * 64];
  const int bid = blockIdx.x;
  if (bid < 128) {            // Q: 32x4 tiles
    int m0 = (bid >> 2) * 128, n0 = (bid & 3) * 128;
    proj_tile<true>(q, WThi, Qhi, Qlo, m0, n0, smAh, smAl, smBh);
  } else if (bid < 192) {     // K: 16x4 tiles
    int b2 = bid - 128;
    int m0 = (b2 >> 2) * 128, n0 = (b2 & 3) * 128;
    proj_tile<true>(k, WThi + (size_t)DM * DM, Khi, Klo, m0, n0, smAh, smAl, smBh);
  } else {                    // V: 16x4 tiles
    int b2 = bid - 192;
    int m0 = (b2 >> 2) * 128, n0 = (b2 & 3) * 128;
    proj_tile<false>(v, WThi + (size_t)2 * DM * DM, Vb, nullptr, m0, n0,
                     smAh, smAl, smBh);
  }
}

// ---------- output projection: 64x128 tiles, 256 blocks, 4 waves (all N)
__global__ __launch_bounds__(256) void outproj_kernel(
    const bf16* __restrict__ AO, const bf16* __restrict__ Bo,
    float* __restrict__ out) {
  __shared__ bf16 smA[64 * 64];
  __shared__ bf16 smB[128 * 64];
  const int bid = blockIdx.x;
  const int m0 = (bid >> 2) * 64, n0 = (bid & 3) * 128;
  const int t = threadIdx.x;
  const int lane = t & 63;
  const int w = t >> 6;            // 0..3
  const int ln = lane & 15, hi4 = lane >> 4;
  const f32x4 zf = {0.f, 0.f, 0.f, 0.f};
  f32x4 acc[4][2];
#pragma unroll
  for (int a = 0; a < 4; ++a)
#pragma unroll
    for (int b = 0; b < 2; ++b) acc[a][b] = zf;

  for (int k0 = 0; k0 < 512; k0 += 64) {
    bf16x8 av[2], bv[4];
#pragma unroll
    for (int i = 0; i < 2; ++i) {
      int idx = i * 256 + t;        // 512 units of A
      int r = idx >> 3, u = idx & 7;
      av[i] = *(const bf16x8*)(AO + (size_t)(m0 + r) * 512 + k0 + u * 8);
    }
#pragma unroll
    for (int i = 0; i < 4; ++i) {
      int idx = i * 256 + t;        // 1024 units of B
      int r = idx >> 3, u = idx & 7;
      bv[i] = *(const bf16x8*)(Bo + (size_t)(n0 + r) * 512 + k0 + u * 8);
    }
    __syncthreads();
#pragma unroll
    for (int i = 0; i < 2; ++i) {
      int idx = i * 256 + t;
      int r = idx >> 3, u = idx & 7;
      *(bf16x8*)&smA[r * 64 + ((u ^ (r & 7)) * 8)] = av[i];
    }
#pragma unroll
    for (int i = 0; i < 4; ++i) {
      int idx = i * 256 + t;
      int r = idx >> 3, u = idx & 7;
      *(bf16x8*)&smB[r * 64 + ((u ^ (r & 7)) * 8)] = bv[i];
    }
    __syncthreads();
#pragma unroll
    for (int kk = 0; kk < 64; kk += 32) {
      const int ub = kk >> 3;
      bf16x8 af[4], bh[2];
#pragma unroll
      for (int mf = 0; mf < 4; ++mf) {
        int row = mf * 16 + ln;
        af[mf] = *(const bf16x8*)&smA[row * 64 + (((ub + hi4) ^ (ln & 7)) * 8)];
      }
#pragma unroll
      for (int nf = 0; nf < 2; ++nf) {
        int row = w * 32 + nf * 16 + ln;
        bh[nf] = *(const bf16x8*)&smB[row * 64 + (((ub + hi4) ^ (ln & 7)) * 8)];
      }
#pragma unroll
      for (int mf = 0; mf < 4; ++mf)
#pragma unroll
        for (int nf = 0; nf < 2; ++nf)
          acc[mf][nf] = mfma_bf16(af[mf], bh[nf], acc[mf][nf]);
    }
  }
#pragma unroll
  for (int mf = 0; mf < 4; ++mf)
#pragma unroll
    for (int nf = 0; nf < 2; ++nf)
#pragma unroll
      for (int e = 0; e < 4; ++e)
        out[(size_t)(m0 + mf * 16 + hi4 * 4 + e) * 512 +
            n0 + w * 32 + nf * 16 + ln] = acc[mf][nf][e];
}

// ---------- banded attention: one (b,h,128-query tile) per block, 512 thr
__global__ __launch_bounds__(512, 2) void attn_kernel(
    const bf16* __restrict__ Qhi, const bf16* __restrict__ Qlo,
    const bf16* __restrict__ Khi, const bf16* __restrict__ Klo,
    const bf16* __restrict__ Vb, bf16* __restrict__ AO) {
  __shared__ bf16 smQh[128 * 64];
  __shared__ bf16 smQl[128 * 64];
  __shared__ bf16 smKh[128 * 64];
  __shared__ bf16 smKl[128 * 64];
  __shared__ bf16 smVt[64 * 128];   // [d][p], swizzled
  __shared__ bf16 smP[128 * 128];   // swizzled
  const int bid = blockIdx.x;
  const int qt = bid & 15;
  const int h  = (bid >> 4) & 7;
  const int b  = bid >> 7;
  const int j0 = qt * 128;
  const int pbase = (j0 >> 1) - 63;  // KV rows pbase..pbase+127
  const int t = threadIdx.x;
  const int lane = t & 63, w = t >> 6;   // 8 waves, 16 q-rows each
  const int ln = lane & 15, hi4 = lane >> 4;

  // stage Q,K (hi/lo, swizzled [128][64]) and V transposed (swizzled [64][128])
#pragma unroll
  for (int i = 0; i < 2; ++i) {
    int idx = i * 512 + t;          // 1024 units
    int r = idx >> 3, u = idx & 7;
    int sw = r * 64 + ((u ^ (r & 7)) * 8);
    size_t qoff = ((size_t)(b * LQn + j0 + r)) * 512 + h * 64 + u * 8;
    *(bf16x8*)&smQh[sw] = *(const bf16x8*)(Qhi + qoff);
    *(bf16x8*)&smQl[sw] = *(const bf16x8*)(Qlo + qoff);
    int p = pbase + r;
    p = p < 0 ? 0 : (p > LKVn - 1 ? LKVn - 1 : p);  // clamped rows masked later
    size_t koff = ((size_t)(b * LKVn + p)) * 512 + h * 64 + u * 8;
    *(bf16x8*)&smKh[sw] = *(const bf16x8*)(Khi + koff);
    *(bf16x8*)&smKl[sw] = *(const bf16x8*)(Klo + koff);
    bf16x8 vv = *(const bf16x8*)(Vb + koff);
#pragma unroll
    for (int e = 0; e < 8; ++e) {
      int rv = u * 8 + e;           // d-row of smVt
      smVt[rv * 128 + (((r >> 3) ^ (rv & 15)) * 8) + (r & 7)] = vv[e];
    }
  }
  __syncthreads();

  // S = Q K^T  (this wave: q-rows w*16..w*16+15, all 128 kv cols), 3-term
  const f32x4 zf = {0.f, 0.f, 0.f, 0.f};
  f32x4 s[8];
#pragma unroll
  for (int cf = 0; cf < 8; ++cf) s[cf] = zf;
#pragma unroll
  for (int kk = 0; kk < 64; kk += 32) {
    const int ub = kk >> 3;
    int rowq = w * 16 + ln;
    int addrq = rowq * 64 + (((ub + hi4) ^ (ln & 7)) * 8);
    bf16x8 ah = *(const bf16x8*)&smQh[addrq];
    bf16x8 al = *(const bf16x8*)&smQl[addrq];
#pragma unroll
    for (int cf = 0; cf < 8; ++cf) {
      int rowk = cf * 16 + ln;
      int addrk = rowk * 64 + (((ub + hi4) ^ (ln & 7)) * 8);
      bf16x8 bh = *(const bf16x8*)&smKh[addrk];
      bf16x8 bl = *(const bf16x8*)&smKl[addrk];
      s[cf] = mfma_bf16(ah, bh, s[cf]);
      s[cf] = mfma_bf16(ah, bl, s[cf]);
      s[cf] = mfma_bf16(al, bh, s[cf]);
    }
  }

  // mask + wave-parallel softmax, P -> bf16 LDS (swizzled)
#pragma unroll
  for (int r = 0; r < 4; ++r) {
    int rloc = w * 16 + hi4 * 4 + r;
    int wlo = rloc >> 1;
    int colmin = wlo > -pbase ? wlo : -pbase;
    int colmax = wlo + 63;
    float sv[8];
    float mx = -1e30f;
#pragma unroll
    for (int cf = 0; cf < 8; ++cf) {
      int col = cf * 16 + ln;
      float val = s[cf][r];
      bool ok = (col >= colmin) && (col <= colmax);
      sv[cf] = ok ? val : -1e30f;
      mx = fmaxf(mx, sv[cf]);
    }
#pragma unroll
    for (int msk = 1; msk < 16; msk <<= 1) mx = fmaxf(mx, __shfl_xor(mx, msk, 64));
    float sum = 0.f;
#pragma unroll
    for (int cf = 0; cf < 8; ++cf) {
      sv[cf] = __expf(sv[cf] - mx);
      sum += sv[cf];
    }
#pragma unroll
    for (int msk = 1; msk < 16; msk <<= 1) sum += __shfl_xor(sum, msk, 64);
    float rs = 1.0f / sum;
#pragma unroll
    for (int cf = 0; cf < 8; ++cf) {
      int uu = cf * 2 + (ln >> 3);
      smP[rloc * 128 + ((uu ^ (rloc & 15)) * 8) + (ln & 7)] = (bf16)(sv[cf] * rs);
    }
  }
  __syncthreads();

  // O = P @ V   (wave's 16 q-rows x 64 d)
  f32x4 o[4];
#pragma unroll
  for (int nf = 0; nf < 4; ++nf) o[nf] = zf;
#pragma unroll
  for (int kk = 0; kk < 128; kk += 32) {
    const int ub = kk >> 3;
    int rowp = w * 16 + ln;
    bf16x8 pa = *(const bf16x8*)&smP[rowp * 128 + (((ub + hi4) ^ ln) * 8)];
#pragma unroll
    for (int nf = 0; nf < 4; ++nf) {
      int d = nf * 16 + ln;
      bf16x8 vf = *(const bf16x8*)&smVt[d * 128 + (((ub + hi4) ^ ln) * 8)];
      o[nf] = mfma_bf16(pa, vf, o[nf]);
    }
  }

  // write AO[b, j0+rloc, h*64 + d]
#pragma unroll
  for (int nf = 0; nf < 4; ++nf)
#pragma unroll
    for (int e = 0; e < 4; ++e) {
      int rloc = w * 16 + hi4 * 4 + e;
      AO[((size_t)(b * LQn + j0 + rloc)) * 512 + h * 64 + nf * 16 + ln] =
          (bf16)o[nf][e];
    }
}

extern "C" void kernel_launch(void* const* d_in, const int* in_sizes, int n_in,
                              void* d_out, int out_size, void* d_ws, size_t ws_size,
                              hipStream_t stream) {
  const float* q    = (const float*)d_in[0];
  const float* k    = (const float*)d_in[1];
  const float* v    = (const float*)d_in[2];
  const float* Wq   = (const float*)d_in[3];
  const float* Wk   = (const float*)d_in[4];
  const float* Wv   = (const float*)d_in[5];
  const float* Wout = (const float*)d_in[6];
  float* out = (float*)d_out;

  char* ws = (char*)d_ws;
  bf16* WThi = (bf16*)ws;                          // 4*512*512*2 = 2 MB
  bf16* Qhi  = (bf16*)(ws + (size_t)(2  << 20));   // 4096*512*2 = 4 MB
  bf16* Qlo  = (bf16*)(ws + (size_t)(6  << 20));   // 4 MB
  bf16* Khi  = (bf16*)(ws + (size_t)(10 << 20));   // 2 MB
  bf16* Klo  = (bf16*)(ws + (size_t)(12 << 20));   // 2 MB
  bf16* Vbuf = (bf16*)(ws + (size_t)(14 << 20));   // 2 MB
  bf16* AO   = (bf16*)(ws + (size_t)(16 << 20));   // 4 MB  (total 20 MB)

  transpose_w_kernel<<<256, 256, 0, stream>>>(Wq, Wk, Wv, Wout, WThi);
  proj_kernel<<<256, 512, 0, stream>>>(q, k, v, WThi, Qhi, Qlo, Khi, Klo, Vbuf);
  attn_kernel<<<256, 512, 0, stream>>>(Qhi, Qlo, Khi, Klo, Vbuf, AO);
  outproj_kernel<<<256, 256, 0, stream>>>(AO, WThi + (size_t)3 * DM * DM, out);
}